// Round 3
// baseline (470.782 us; speedup 1.0000x reference)
//
#include <hip/hip_runtime.h>
#include <math.h>

// Problem constants (fixed by setup_inputs)
//   kv_cache: (2048 pages, 2, 16, 8, 128) f32
//   k, v:     (4, 2048, 8, 128) f32
//   query_lens: int32[4]
//   PAGE_SIZE=16, STREAMING_BUDGET=4096, NUM_SINK=4, CTX=3072, SEQ=2048
//   per-batch positions: 8192 (512 pages), B=4, H=8, D=128
//
// Output: (2048, 2, 16, 8, 128) f32 — same layout as kv_cache.
// Total f4 elements: 67,108,864 / 4 = 16,777,216.

#define TOTAL_F4 16777216u
#define ROPE_P 4096
#define ROPE_J 64
// log2(10000)/64
#define LOG2_1E4_OVER_64 0.20762050593045951f

__global__ __launch_bounds__(256) void rope_table_k(float2* __restrict__ tab) {
    int i = blockIdx.x * 256 + threadIdx.x;
    if (i >= ROPE_P * ROPE_J) return;
    int p = i >> 6;
    int j = i & 63;
    float inv = exp2f(-LOG2_1E4_OVER_64 * (float)j);   // 10000^(-j/64)
    float ang = (float)p * inv;
    float s, c;
    sincosf(ang, &s, &c);                               // accurate version (range reduction)
    tab[i] = make_float2(c, s);
}

__global__ __launch_bounds__(256) void kvcache_k(
    const float4* __restrict__ cache,   // (2048,2,16,8,128) -> f4 strides: page 8192, kv 4096, slot 256, h 32
    const float4* __restrict__ kin,     // (4,2048,8,128)    -> f4 strides: b 524288, s 256, h 32
    const float4* __restrict__ vin,
    const int*    __restrict__ qls,
    const float2* __restrict__ rope,    // [4096][64] (cos,sin), may be null -> inline sincos
    float4*       __restrict__ out)
{
    const unsigned stride = gridDim.x * 256u;
    for (unsigned i = blockIdx.x * 256u + threadIdx.x; i < TOTAL_F4; i += stride) {
        unsigned d4   = i & 31u;          // d = 4*d4
        unsigned h    = (i >> 5) & 7u;
        unsigned slot = (i >> 8) & 15u;
        unsigned kv   = (i >> 12) & 1u;
        unsigned page = i >> 13;
        unsigned b    = page >> 9;        // 512 pages per batch
        unsigned p    = ((page & 511u) << 4) | slot;   // position within batch, [0,8192)

        int ql = qls[b];
        // rolling <=> 3072 + ql > 4096 <=> ql > 1024
        bool rolling = ql > 1024;

        int  ip      = (int)p;
        int  srcp    = ip;
        bool from_new = false;
        if (rolling) {
            if (ip >= 4 && ip < 4096 - ql) {
                srcp = ip + ql - 1024;            // shift_src = p + (ql-1020) - 4
            } else if (ip >= 4096 - ql && ip < 4096) {
                from_new = true;
                srcp = ip - (4096 - ql);          // append
            }
        } else if (ql > 0) {
            if (ip >= 3072 && ip < 3072 + ql) {
                from_new = true;
                srcp = ip - 3072;                 // plain append
            }
        }
        // clip (no-op for this problem's parameters, kept for safety)
        if (srcp < 0) srcp = 0;
        if (from_new) { if (srcp > 2047) srcp = 2047; }
        else          { if (srcp > 8191) srcp = 8191; }

        float4 x;
        if (from_new) {
            const float4* nb = kv ? vin : kin;
            x = nb[(size_t)b * 524288u + (size_t)srcp * 256u + h * 32u + d4];
        } else {
            unsigned g = b * 8192u + (unsigned)srcp;
            x = cache[(size_t)(g >> 4) * 8192u + (size_t)kv * 4096u
                      + (g & 15u) * 256u + h * 32u + d4];
        }

        // RoPE on keys at positions < STREAMING_BUDGET (wave-uniform condition)
        if (kv == 0u && p < 4096u) {
            // partner lane holds the other half (d4 ^ 16): same page/kv/slot/h
            float4 y;
            y.x = __shfl_xor(x.x, 16);
            y.y = __shfl_xor(x.y, 16);
            y.z = __shfl_xor(x.z, 16);
            y.w = __shfl_xor(x.w, 16);

            unsigned jb = (d4 & 15u) * 4u;        // freq index base, [0,64)
            float2 cs[4];
            if (rope) {
                const float2* rp = rope + (size_t)p * 64u + jb;
                cs[0] = rp[0]; cs[1] = rp[1]; cs[2] = rp[2]; cs[3] = rp[3];
            } else {
#pragma unroll
                for (int q = 0; q < 4; ++q) {
                    float inv = exp2f(-LOG2_1E4_OVER_64 * (float)(jb + (unsigned)q));
                    sincosf((float)p * inv, &cs[q].y, &cs[q].x);
                }
            }

            float4 r;
            if (d4 < 16u) {
                // lower half: out = x1*cos - x2*sin   (x1 = own, x2 = partner)
                r.x = x.x * cs[0].x - y.x * cs[0].y;
                r.y = x.y * cs[1].x - y.y * cs[1].y;
                r.z = x.z * cs[2].x - y.z * cs[2].y;
                r.w = x.w * cs[3].x - y.w * cs[3].y;
            } else {
                // upper half: out = x1*sin + x2*cos   (x1 = partner, x2 = own)
                r.x = y.x * cs[0].y + x.x * cs[0].x;
                r.y = y.y * cs[1].y + x.y * cs[1].x;
                r.z = y.z * cs[2].y + x.z * cs[2].x;
                r.w = y.w * cs[3].y + x.w * cs[3].x;
            }
            x = r;
        }

        out[i] = x;
    }
}

extern "C" void kernel_launch(void* const* d_in, const int* in_sizes, int n_in,
                              void* d_out, int out_size, void* d_ws, size_t ws_size,
                              hipStream_t stream) {
    const float4* cache = (const float4*)d_in[0];
    const float4* kin   = (const float4*)d_in[1];
    const float4* vin   = (const float4*)d_in[2];
    const int*    qls   = (const int*)d_in[3];
    float4*       out   = (float4*)d_out;

    float2* rope = nullptr;
    if (ws_size >= (size_t)ROPE_P * ROPE_J * sizeof(float2)) {
        rope = (float2*)d_ws;
        rope_table_k<<<(ROPE_P * ROPE_J + 255) / 256, 256, 0, stream>>>(rope);
    }

    // 16.8M f4 items; 16384 blocks x 256 threads -> 4 iters/thread
    kvcache_k<<<16384, 256, 0, stream>>>(cache, kin, vin, qls, rope, out);
}

// Round 4
// 453.887 us; speedup vs baseline: 1.0372x; 1.0372x over previous
//
#include <hip/hip_runtime.h>
#include <math.h>

// StreamingKVCache — gather/shift/append + RoPE(keys, p<4096) over paged KV.
//   kv_cache: (2048 pages, 2, 16, 8, 128) f32  -> out same layout (268 MB)
//   k, v:     (4, 2048, 8, 128) f32
//   query_lens: int32[4] = {2048,1536,1024,512} at bench time (code handles any)
//   B=4, 8192 positions per batch (512 pages), H=8, D=128
// Memory-bound: ~538 MB total traffic -> ~85 us @ 6.3 TB/s.

typedef float f32x4 __attribute__((ext_vector_type(4)));

#define TOTAL_F4   16777216u   // 2048*2*16*8*128 / 4
#define GRID_BLKS  16384
#define ITER_SPAN  4194304u    // GRID_BLKS*256 == 2^22 == one batch's f4 span
#define ROPE_P 4096
#define ROPE_J 64
// log2(10000)/64
#define LOG2_1E4_OVER_64 0.20762050593045951f

__global__ __launch_bounds__(256) void rope_table_k(float2* __restrict__ tab) {
    int i = blockIdx.x * 256 + threadIdx.x;
    if (i >= ROPE_P * ROPE_J) return;
    int p = i >> 6;
    int j = i & 63;
    float inv = exp2f(-LOG2_1E4_OVER_64 * (float)j);   // 10000^(-j/64)
    float s, c;
    sincosf((float)p * inv, &s, &c);
    tab[i] = make_float2(c, s);
}

__global__ __launch_bounds__(256) void kvcache_k(
    const f32x4* __restrict__ cache,   // f4 strides: page 8192, kv 4096, slot 256, h 32
    const f32x4* __restrict__ kin,     // f4 strides: b 524288, s 256, h 32
    const f32x4* __restrict__ vin,
    const int*   __restrict__ qls,
    const float2* __restrict__ rope,   // [4096][64] (cos,sin)
    f32x4*       __restrict__ out)
{
    const unsigned base = blockIdx.x * 256u + threadIdx.x;

#pragma unroll
    for (int it = 0; it < 4; ++it) {
        // i = base + it*2^22  ->  batch b == it (compile-time constant)
        const unsigned i = base + (unsigned)it * ITER_SPAN;
        const unsigned d4   = i & 31u;           // d = 4*d4
        const unsigned h    = (i >> 5) & 7u;
        const unsigned slot = (i >> 8) & 15u;
        const unsigned kv   = (i >> 12) & 1u;
        const unsigned page = i >> 13;
        const unsigned p    = ((page & 511u) << 4) | slot;  // position in batch [0,8192)

        const int ql = qls[it];                  // wave-uniform scalar
        const bool rolling = ql > 1024;          // 3072 + ql > 4096

        int  srcp = (int)p;
        bool from_new = false;
        if (rolling) {
            if ((int)p >= 4 && (int)p < 4096 - ql) {
                srcp = (int)p + ql - 1024;       // shift: p + (ql-1020) - 4
            } else if ((int)p >= 4096 - ql && (int)p < 4096) {
                from_new = true;
                srcp = (int)p - (4096 - ql);     // rolling append
            }
        } else if (ql > 0) {
            if ((int)p >= 3072 && (int)p < 3072 + ql) {
                from_new = true;
                srcp = (int)p - 3072;            // plain append
            }
        }
        if (srcp < 0) srcp = 0;
        if (from_new) { if (srcp > 2047) srcp = 2047; }
        else          { if (srcp > 8191) srcp = 8191; }

        f32x4 x;
        if (from_new) {
            const f32x4* nb = kv ? vin : kin;
            x = __builtin_nontemporal_load(
                    &nb[(size_t)it * 524288u + (size_t)srcp * 256u + h * 32u + d4]);
        } else {
            const unsigned g = (unsigned)it * 8192u + (unsigned)srcp;
            x = __builtin_nontemporal_load(
                    &cache[(size_t)(g >> 4) * 8192u + (size_t)kv * 4096u
                           + (g & 15u) * 256u + h * 32u + d4]);
        }

        // RoPE on keys at positions < 4096 (condition wave-uniform)
        if (kv == 0u && p < 4096u) {
            // partner lane (d4^16) holds the other half of the head-dim; same p/h
            f32x4 y;
            y[0] = __shfl_xor(x[0], 16);
            y[1] = __shfl_xor(x[1], 16);
            y[2] = __shfl_xor(x[2], 16);
            y[3] = __shfl_xor(x[3], 16);

            const unsigned jb = (d4 & 15u) * 4u;            // freq base [0,64)
            const f32x4* rp = (const f32x4*)(rope + (size_t)p * 64u + jb);
            const f32x4 cs01 = rp[0];   // c0 s0 c1 s1
            const f32x4 cs23 = rp[1];   // c2 s2 c3 s3

            f32x4 r;
            if (d4 < 16u) {             // lower half: x1*cos - x2*sin
                r[0] = x[0] * cs01[0] - y[0] * cs01[1];
                r[1] = x[1] * cs01[2] - y[1] * cs01[3];
                r[2] = x[2] * cs23[0] - y[2] * cs23[1];
                r[3] = x[3] * cs23[2] - y[3] * cs23[3];
            } else {                    // upper half: x1*sin + x2*cos
                r[0] = y[0] * cs01[1] + x[0] * cs01[0];
                r[1] = y[1] * cs01[3] + x[1] * cs01[2];
                r[2] = y[2] * cs23[1] + x[2] * cs23[0];
                r[3] = y[3] * cs23[3] + x[3] * cs23[2];
            }
            x = r;
        }

        __builtin_nontemporal_store(x, &out[i]);
    }
}

extern "C" void kernel_launch(void* const* d_in, const int* in_sizes, int n_in,
                              void* d_out, int out_size, void* d_ws, size_t ws_size,
                              hipStream_t stream) {
    const f32x4* cache = (const f32x4*)d_in[0];
    const f32x4* kin   = (const f32x4*)d_in[1];
    const f32x4* vin   = (const f32x4*)d_in[2];
    const int*   qls   = (const int*)d_in[3];
    f32x4*       out   = (f32x4*)d_out;

    float2* rope = (float2*)d_ws;   // 2 MB table, ws is plenty
    rope_table_k<<<(ROPE_P * ROPE_J + 255) / 256, 256, 0, stream>>>(rope);

    kvcache_k<<<GRID_BLKS, 256, 0, stream>>>(cache, kin, vin, qls, rope, out);
}